// Round 1
// baseline (319.429 us; speedup 1.0000x reference)
//
#include <hip/hip_runtime.h>
#include <math.h>

// ============================================================
// Small dense linear algebra in double precision (per-thread).
// 9x9 symmetric stored packed lower-tri: M[i*(i+1)/2 + j], j<=i.
// ============================================================

__device__ __forceinline__ void chol9(double* M) {
#pragma unroll
  for (int i = 0; i < 9; ++i) {
    const int ib = i * (i + 1) / 2;
#pragma unroll
    for (int j = 0; j <= i; ++j) {
      const int jb = j * (j + 1) / 2;
      double s = M[ib + j];
#pragma unroll
      for (int k = 0; k < j; ++k) s -= M[ib + k] * M[jb + k];
      if (j == i)
        M[ib + j] = sqrt(fmax(s, 1e-300));
      else
        M[ib + j] = s / M[jb + j];
    }
  }
}

__device__ __forceinline__ void cholsolve9(const double* L, double* x) {
#pragma unroll
  for (int i = 0; i < 9; ++i) {
    const int ib = i * (i + 1) / 2;
    double s = x[i];
#pragma unroll
    for (int k = 0; k < i; ++k) s -= L[ib + k] * x[k];
    x[i] = s / L[ib + i];
  }
#pragma unroll
  for (int i = 8; i >= 0; --i) {
    double s = x[i];
#pragma unroll
    for (int k = i + 1; k < 9; ++k) s -= L[k * (k + 1) / 2 + i] * x[k];
    x[i] = s / L[i * (i + 1) / 2 + i];
  }
}

// Smallest-eigenvalue eigenvector of symmetric 3x3 via cyclic Jacobi.
__device__ __forceinline__ void smallest_evec3(const double G[3][3], double v3[3]) {
  double a[3][3] = {{G[0][0], G[0][1], G[0][2]},
                    {G[1][0], G[1][1], G[1][2]},
                    {G[2][0], G[2][1], G[2][2]}};
  double V[3][3] = {{1, 0, 0}, {0, 1, 0}, {0, 0, 1}};
  for (int sweep = 0; sweep < 15; ++sweep) {
#pragma unroll
    for (int p = 0; p < 2; ++p) {
#pragma unroll
      for (int q = p + 1; q < 3; ++q) {
        double apq = a[p][q];
        if (fabs(apq) < 1e-300) continue;
        double tau = (a[q][q] - a[p][p]) / (2.0 * apq);
        double t = ((tau >= 0.0) ? 1.0 : -1.0) / (fabs(tau) + sqrt(1.0 + tau * tau));
        double c = 1.0 / sqrt(1.0 + t * t);
        double s = t * c;
#pragma unroll
        for (int k = 0; k < 3; ++k) {  // A = A*J
          double akp = a[k][p], akq = a[k][q];
          a[k][p] = c * akp - s * akq;
          a[k][q] = s * akp + c * akq;
        }
#pragma unroll
        for (int k = 0; k < 3; ++k) {  // A = J^T*A
          double apk = a[p][k], aqk = a[q][k];
          a[p][k] = c * apk - s * aqk;
          a[q][k] = s * apk + c * aqk;
        }
#pragma unroll
        for (int k = 0; k < 3; ++k) {  // V = V*J
          double vkp = V[k][p], vkq = V[k][q];
          V[k][p] = c * vkp - s * vkq;
          V[k][q] = s * vkp + c * vkq;
        }
      }
    }
  }
  // pick column of min diagonal with constant indices (keep V in registers)
  double mv = a[0][0];
  double v0 = V[0][0], v1 = V[1][0], v2 = V[2][0];
  if (a[1][1] < mv) { mv = a[1][1]; v0 = V[0][1]; v1 = V[1][1]; v2 = V[2][1]; }
  if (a[2][2] < mv) { mv = a[2][2]; v0 = V[0][2]; v1 = V[1][2]; v2 = V[2][2]; }
  v3[0] = v0; v3[1] = v1; v3[2] = v2;
}

// From accumulated AtA (packed, destroyed) + normalization params -> F (9 floats).
// Steps: null vector of AtA (shifted Cholesky + inverse iteration), rank-2
// projection F' = F (I - v3 v3^T), denormalize T2^T F' T1, divide by [2][2].
__device__ __forceinline__ void solveF(double* M, double s1, double m1x, double m1y,
                                       double s2, double m2x, double m2y,
                                       float* out) {
  double tr = M[0] + M[2] + M[5] + M[9] + M[14] + M[20] + M[27] + M[35] + M[44];
  double shift = 1e-12 * tr;
  M[0] += shift; M[2] += shift; M[5] += shift; M[9] += shift; M[14] += shift;
  M[20] += shift; M[27] += shift; M[35] += shift; M[44] += shift;
  chol9(M);
  double x[9];
#pragma unroll
  for (int i = 0; i < 9; ++i) x[i] = 1.0;
  for (int t = 0; t < 6; ++t) {
    cholsolve9(M, x);
    double n = 0.0;
#pragma unroll
    for (int i = 0; i < 9; ++i) n += x[i] * x[i];
    n = 1.0 / sqrt(n);
#pragma unroll
    for (int i = 0; i < 9; ++i) x[i] *= n;
  }
  double F0[3][3] = {{x[0], x[1], x[2]}, {x[3], x[4], x[5]}, {x[6], x[7], x[8]}};
  double G[3][3];
#pragma unroll
  for (int i = 0; i < 3; ++i)
#pragma unroll
    for (int j = 0; j < 3; ++j)
      G[i][j] = F0[0][i] * F0[0][j] + F0[1][i] * F0[1][j] + F0[2][i] * F0[2][j];
  double v3[3];
  smallest_evec3(G, v3);
  double Fv[3];
#pragma unroll
  for (int i = 0; i < 3; ++i)
    Fv[i] = F0[i][0] * v3[0] + F0[i][1] * v3[1] + F0[i][2] * v3[2];
  double F2[3][3];
#pragma unroll
  for (int i = 0; i < 3; ++i)
#pragma unroll
    for (int j = 0; j < 3; ++j) F2[i][j] = F0[i][j] - Fv[i] * v3[j];
  // rows: T2^T * F2
  double R[3][3];
#pragma unroll
  for (int j = 0; j < 3; ++j) {
    R[0][j] = s2 * F2[0][j];
    R[1][j] = s2 * F2[1][j];
    R[2][j] = -s2 * m2x * F2[0][j] - s2 * m2y * F2[1][j] + F2[2][j];
  }
  // cols: R * T1
  double Ff[3][3];
#pragma unroll
  for (int i = 0; i < 3; ++i) {
    Ff[i][0] = s1 * R[i][0];
    Ff[i][1] = s1 * R[i][1];
    Ff[i][2] = -s1 * m1x * R[i][0] - s1 * m1y * R[i][1] + R[i][2];
  }
  double inv = 1.0 / Ff[2][2];
#pragma unroll
  for (int i = 0; i < 3; ++i)
#pragma unroll
    for (int j = 0; j < 3; ++j) out[3 * i + j] = (float)(Ff[i][j] * inv);
}

// ============================================================
// Kernel 1: one thread per RANSAC iteration -> model F (9 floats) + uniq flag
// ============================================================
__global__ __launch_bounds__(64) void fit_models(
    const float* __restrict__ pts1, const float* __restrict__ pts2,
    const int* __restrict__ samples, float* __restrict__ models,
    int* __restrict__ uflag, int iters) {
  const int it = blockIdx.x * 64 + threadIdx.x;
  if (it >= iters) return;
  int idx[8];
#pragma unroll
  for (int k = 0; k < 8; ++k) idx[k] = samples[it * 8 + k];
  // uniqueness: all-pairs compare (equivalent to sorted-adjacent check)
  int u = 1;
#pragma unroll
  for (int a = 0; a < 8; ++a)
#pragma unroll
    for (int b = a + 1; b < 8; ++b)
      if (idx[a] == idx[b]) u = 0;
  uflag[it] = u;

  float X1[8], Y1[8], Z1[8], X2[8], Y2[8], Z2[8];
#pragma unroll
  for (int k = 0; k < 8; ++k) {
    const int j = idx[k];
    X1[k] = pts1[3 * j];     Y1[k] = pts1[3 * j + 1]; Z1[k] = pts1[3 * j + 2];
    X2[k] = pts2[3 * j];     Y2[k] = pts2[3 * j + 1]; Z2[k] = pts2[3 * j + 2];
  }
  // Hartley normalization (w == 1 for all 8 points)
  double sx1 = 0, sy1 = 0, sx2 = 0, sy2 = 0;
#pragma unroll
  for (int k = 0; k < 8; ++k) {
    sx1 += (double)X1[k]; sy1 += (double)Y1[k];
    sx2 += (double)X2[k]; sy2 += (double)Y2[k];
  }
  const double m1x = sx1 / 8.0, m1y = sy1 / 8.0;
  const double m2x = sx2 / 8.0, m2y = sy2 / 8.0;
  double sd1 = 0, sd2 = 0;
#pragma unroll
  for (int k = 0; k < 8; ++k) {
    double dx1 = (double)X1[k] - m1x, dy1 = (double)Y1[k] - m1y;
    double dx2 = (double)X2[k] - m2x, dy2 = (double)Y2[k] - m2y;
    sd1 += sqrt(dx1 * dx1 + dy1 * dy1);
    sd2 += sqrt(dx2 * dx2 + dy2 * dy2);
  }
  const double s1 = sqrt(2.0) / (sd1 / 8.0 + 1e-8);
  const double s2 = sqrt(2.0) / (sd2 / 8.0 + 1e-8);

  double M[45];
#pragma unroll
  for (int r = 0; r < 45; ++r) M[r] = 0.0;
#pragma unroll
  for (int k = 0; k < 8; ++k) {
    const double z1 = (double)Z1[k], z2 = (double)Z2[k];
    const double p1x = s1 * ((double)X1[k] - m1x * z1);
    const double p1y = s1 * ((double)Y1[k] - m1y * z1);
    const double p2x = s2 * ((double)X2[k] - m2x * z2);
    const double p2y = s2 * ((double)Y2[k] - m2y * z2);
    const double a[9] = {p2x * p1x, p2x * p1y, p2x * z1,
                         p2y * p1x, p2y * p1y, p2y * z1,
                         z2 * p1x,  z2 * p1y,  z2 * z1};
#pragma unroll
    for (int i = 0; i < 9; ++i)
#pragma unroll
      for (int j = 0; j <= i; ++j) M[i * (i + 1) / 2 + j] += a[i] * a[j];
  }
  solveF(M, s1, m1x, m1y, s2, m2x, m2y, models + (size_t)it * 9);
}

// ============================================================
// Sampson error (fp32, mirrors the reference einsums)
// ============================================================
__device__ __forceinline__ float sampson_err(const float* __restrict__ F,
                                             float x1, float y1, float z1,
                                             float x2, float y2, float z2) {
  float a0 = F[0] * x1 + F[1] * y1 + F[2] * z1;
  float a1 = F[3] * x1 + F[4] * y1 + F[5] * z1;
  float a2 = F[6] * x1 + F[7] * y1 + F[8] * z1;
  float b0 = F[0] * x2 + F[3] * y2 + F[6] * z2;
  float b1 = F[1] * x2 + F[4] * y2 + F[7] * z2;
  float d = x2 * a0 + y2 * a1 + z2 * a2;
  float den = a0 * a0 + a1 * a1 + b0 * b0 + b1 * b1;
  return (d * d) / den;
}

// Kernel 2: one block per model; inlier count + sum(sqrt(err)) over all points
__global__ __launch_bounds__(256) void sampson_stats(
    const float* __restrict__ pts1, const float* __restrict__ pts2,
    const float* __restrict__ models, float* __restrict__ ml,
    float* __restrict__ ssum, int N) {
  const int it = blockIdx.x;
  float F[9];
#pragma unroll
  for (int r = 0; r < 9; ++r) F[r] = models[(size_t)it * 9 + r];
  float cnt = 0.f, ss = 0.f;
  for (int i = threadIdx.x; i < N; i += 256) {
    float x1 = pts1[3 * i], y1 = pts1[3 * i + 1], z1 = pts1[3 * i + 2];
    float x2 = pts2[3 * i], y2 = pts2[3 * i + 1], z2 = pts2[3 * i + 2];
    float err = sampson_err(F, x1, y1, z1, x2, y2, z2);
    if (err <= 1.0f) {
      cnt += 1.0f;
      ss += sqrtf(err);
    }
  }
#pragma unroll
  for (int o = 32; o > 0; o >>= 1) {
    cnt += __shfl_down(cnt, o);
    ss += __shfl_down(ss, o);
  }
  __shared__ float sc[4], sv[4];
  const int lane = threadIdx.x & 63, wv = threadIdx.x >> 6;
  if (lane == 0) { sc[wv] = cnt; sv[wv] = ss; }
  __syncthreads();
  if (threadIdx.x == 0) {
    ml[it] = sc[0] + sc[1] + sc[2] + sc[3];
    ssum[it] = sv[0] + sv[1] + sv[2] + sv[3];
  }
}

// ============================================================
// Kernel 3: scores + argmax (first-index tie-break like jnp.argmax)
// ============================================================
__global__ __launch_bounds__(256) void select_best(
    const float* __restrict__ ml, const float* __restrict__ ssum,
    const int* __restrict__ uniq, int iters, int* __restrict__ best) {
  const int tid = threadIdx.x;
  __shared__ float ra[256], rb[256];
  __shared__ int rid[256];
  float mlmax = 0.f, mnmax = -INFINITY;
  for (int i = tid; i < iters; i += 256) {
    if (uniq[i]) {
      float m = ml[i];
      mlmax = fmaxf(mlmax, m);
      float mean = (ssum[i] + 1e-8f) / (m + 1e-8f);
      mnmax = fmaxf(mnmax, mean);
    }
  }
  ra[tid] = mlmax;
  rb[tid] = mnmax;
  __syncthreads();
  for (int s = 128; s > 0; s >>= 1) {
    if (tid < s) {
      ra[tid] = fmaxf(ra[tid], ra[tid + s]);
      rb[tid] = fmaxf(rb[tid], rb[tid + s]);
    }
    __syncthreads();
  }
  const float MLMAX = ra[0];
  const float MNMAX = rb[0];
  __syncthreads();
  float bsc = -INFINITY;
  int bid = 0x7FFFFFFF;
  for (int i = tid; i < iters; i += 256) {
    float sc = -INFINITY;
    float m = ml[i];
    float mean = (ssum[i] + 1e-8f) / (m + 1e-8f);
    if (uniq[i]) sc = 0.5f * (m / MLMAX) + 0.5f * (1.0f - mean / MNMAX);
    if (sc > bsc || (sc == bsc && i < bid)) { bsc = sc; bid = i; }
  }
  ra[tid] = bsc;
  rid[tid] = bid;
  __syncthreads();
  for (int s = 128; s > 0; s >>= 1) {
    if (tid < s) {
      if (ra[tid + s] > ra[tid] ||
          (ra[tid + s] == ra[tid] && rid[tid + s] < rid[tid])) {
        ra[tid] = ra[tid + s];
        rid[tid] = rid[tid + s];
      }
    }
    __syncthreads();
  }
  if (tid == 0) best[0] = rid[0];
}

// ============================================================
// Kernel 4: write the best model's inlier mask to d_out[9..9+N)
// ============================================================
__global__ __launch_bounds__(256) void write_mask(
    const float* __restrict__ pts1, const float* __restrict__ pts2,
    const float* __restrict__ models, const int* __restrict__ best,
    float* __restrict__ outmask, int N) {
  const int i = blockIdx.x * 256 + threadIdx.x;
  if (i >= N) return;
  const float* F = models + (size_t)best[0] * 9;
  float err = sampson_err(F, pts1[3 * i], pts1[3 * i + 1], pts1[3 * i + 2],
                          pts2[3 * i], pts2[3 * i + 1], pts2[3 * i + 2]);
  outmask[i] = (err <= 1.0f) ? 1.0f : 0.0f;
}

// ============================================================
// Kernel 5: weighted eight-point over all N points, weights = best mask
// ============================================================
__global__ __launch_bounds__(256) void final_fit(
    const float* __restrict__ pts1, const float* __restrict__ pts2,
    const float* __restrict__ mask, float* __restrict__ outF, int N) {
  const int tid = threadIdx.x;
  const int lane = tid & 63, wv = tid >> 6;
  __shared__ double tmp4[4];

  auto reduceB = [&](double v) -> double {
#pragma unroll
    for (int o = 32; o > 0; o >>= 1) v += __shfl_down(v, o);
    if (lane == 0) tmp4[wv] = v;
    __syncthreads();
    double r = tmp4[0] + tmp4[1] + tmp4[2] + tmp4[3];
    __syncthreads();
    return r;
  };

  // pass 1: weighted sums for means
  double sw = 0, sx1 = 0, sy1 = 0, sx2 = 0, sy2 = 0;
  for (int i = tid; i < N; i += 256) {
    double w = (double)mask[i];
    if (w != 0.0) {
      sw += w;
      sx1 += w * (double)pts1[3 * i];
      sy1 += w * (double)pts1[3 * i + 1];
      sx2 += w * (double)pts2[3 * i];
      sy2 += w * (double)pts2[3 * i + 1];
    }
  }
  const double WS = reduceB(sw);
  const double M1X = reduceB(sx1) / WS;
  const double M1Y = reduceB(sy1) / WS;
  const double M2X = reduceB(sx2) / WS;
  const double M2Y = reduceB(sy2) / WS;

  // pass 2: weighted mean distances
  double sd1 = 0, sd2 = 0;
  for (int i = tid; i < N; i += 256) {
    double w = (double)mask[i];
    if (w != 0.0) {
      double dx1 = (double)pts1[3 * i] - M1X, dy1 = (double)pts1[3 * i + 1] - M1Y;
      double dx2 = (double)pts2[3 * i] - M2X, dy2 = (double)pts2[3 * i + 1] - M2Y;
      sd1 += w * sqrt(dx1 * dx1 + dy1 * dy1);
      sd2 += w * sqrt(dx2 * dx2 + dy2 * dy2);
    }
  }
  const double S1 = sqrt(2.0) / (reduceB(sd1) / WS + 1e-8);
  const double S2 = sqrt(2.0) / (reduceB(sd2) / WS + 1e-8);

  // pass 3: accumulate AtA (45 packed entries, weight w^2 with w in {0,1})
  double acc[45];
#pragma unroll
  for (int r = 0; r < 45; ++r) acc[r] = 0.0;
  for (int i = tid; i < N; i += 256) {
    double w = (double)mask[i];
    if (w != 0.0) {
      const double z1 = (double)pts1[3 * i + 2], z2 = (double)pts2[3 * i + 2];
      const double p1x = S1 * ((double)pts1[3 * i] - M1X * z1);
      const double p1y = S1 * ((double)pts1[3 * i + 1] - M1Y * z1);
      const double p2x = S2 * ((double)pts2[3 * i] - M2X * z2);
      const double p2y = S2 * ((double)pts2[3 * i + 1] - M2Y * z2);
      const double a[9] = {p2x * p1x, p2x * p1y, p2x * z1,
                           p2y * p1x, p2y * p1y, p2y * z1,
                           z2 * p1x,  z2 * p1y,  z2 * z1};
      const double ww = w * w;
#pragma unroll
      for (int ii = 0; ii < 9; ++ii)
#pragma unroll
        for (int jj = 0; jj <= ii; ++jj)
          acc[ii * (ii + 1) / 2 + jj] += ww * a[ii] * a[jj];
    }
  }
  __shared__ double part[45][4];
#pragma unroll
  for (int r = 0; r < 45; ++r) {
    double v = acc[r];
#pragma unroll
    for (int o = 32; o > 0; o >>= 1) v += __shfl_down(v, o);
    if (lane == 0) part[r][wv] = v;
  }
  __syncthreads();
  if (tid == 0) {
    double M[45];
#pragma unroll
    for (int r = 0; r < 45; ++r)
      M[r] = part[r][0] + part[r][1] + part[r][2] + part[r][3];
    solveF(M, S1, M1X, M1Y, S2, M2X, M2Y, outF);
  }
}

// ============================================================
// Host launcher
// ============================================================
extern "C" void kernel_launch(void* const* d_in, const int* in_sizes, int n_in,
                              void* d_out, int out_size, void* d_ws, size_t ws_size,
                              hipStream_t stream) {
  const float* pts1 = (const float*)d_in[0];
  const float* pts2 = (const float*)d_in[1];
  const int* samples = (const int*)d_in[2];
  const int N = in_sizes[0] / 3;      // 16384
  const int iters = in_sizes[2] / 8;  // 4096 (K = 8 fixed by the algorithm)

  // workspace layout
  float* models = (float*)d_ws;                    // iters*9 floats
  float* ml = models + (size_t)iters * 9;          // iters
  float* ssum = ml + iters;                        // iters
  int* uniq = (int*)(ssum + iters);                // iters
  int* best = uniq + iters;                        // 1

  float* outF = (float*)d_out;      // 9 floats (Mbest)
  float* outmask = outF + 9;        // N floats (0/1)

  fit_models<<<(iters + 63) / 64, 64, 0, stream>>>(pts1, pts2, samples, models,
                                                   uniq, iters);
  sampson_stats<<<iters, 256, 0, stream>>>(pts1, pts2, models, ml, ssum, N);
  select_best<<<1, 256, 0, stream>>>(ml, ssum, uniq, iters, best);
  write_mask<<<(N + 255) / 256, 256, 0, stream>>>(pts1, pts2, models, best,
                                                  outmask, N);
  final_fit<<<1, 256, 0, stream>>>(pts1, pts2, outmask, outF, N);
}